// Round 13
// baseline (345.416 us; speedup 1.0000x reference)
//
#include <hip/hip_runtime.h>
#include <cstdint>
#include <cstddef>

typedef __bf16 bfloat;
typedef __bf16 bf16x8 __attribute__((ext_vector_type(8)));
typedef __bf16 bf16x4 __attribute__((ext_vector_type(4)));
typedef float  f32x4  __attribute__((ext_vector_type(4)));

static constexpr int D  = 1024;
static constexpr int S  = 2048;
static constexpr int B  = 2;
static constexpr int H  = 16;
static constexpr int DH = 64;
static constexpr int M  = B * S;
static constexpr int WMAT_N = 1024 * 1024;

#define MFMA_BF16(a, b, c) __builtin_amdgcn_mfma_f32_16x16x32_bf16((a), (b), (c), 0, 0, 0)

__device__ __forceinline__ void gl_lds16(const void* g, void* l) {
  __builtin_amdgcn_global_load_lds(
      (const __attribute__((address_space(1))) void*)g,
      (__attribute__((address_space(3))) void*)l, 16, 0, 0);
}

// ---- prep: f64 abs-sum of weight y ----
__global__ void prep_kernel(const float* __restrict__ w0, const float* __restrict__ w1,
                            const float* __restrict__ w2, const float* __restrict__ w3,
                            double* __restrict__ sums) {
  const int y = blockIdx.y;
  const float* w = (y == 0) ? w0 : (y == 1) ? w1 : (y == 2) ? w2 : w3;
  const float4* w4 = (const float4*)w;
  double s = 0.0;
  for (int i = blockIdx.x * blockDim.x + threadIdx.x; i < (WMAT_N / 4);
       i += gridDim.x * blockDim.x) {
    float4 v = w4[i];
    s += (double)fabsf(v.x) + (double)fabsf(v.y) + (double)fabsf(v.z) + (double)fabsf(v.w);
  }
  for (int off = 1; off < 64; off <<= 1) s += __shfl_xor(s, off, 64);
  __shared__ double ps[4];
  if ((threadIdx.x & 63) == 0) ps[threadIdx.x >> 6] = s;
  __syncthreads();
  if (threadIdx.x == 0) atomicAdd(&sums[y], ps[0] + ps[1] + ps[2] + ps[3]);
}

// ---------------- ternarize -> bf16 ----------------
__global__ void tern_kernel(const float* __restrict__ w0, const float* __restrict__ w1,
                            const float* __restrict__ w2, const float* __restrict__ w3,
                            bfloat* __restrict__ o0, bfloat* __restrict__ o1,
                            bfloat* __restrict__ o2, bfloat* __restrict__ o3,
                            const double* __restrict__ sums) {
  int z = blockIdx.y;
  const float* w = (z == 0) ? w0 : (z == 1) ? w1 : (z == 2) ? w2 : w3;
  bfloat* o = (z == 0) ? o0 : (z == 1) ? o1 : (z == 2) ? o2 : o3;
  double thr = sums[z] * (1.0 / (double)WMAT_N);
  const float4* w4 = (const float4*)w;
  for (int i = blockIdx.x * blockDim.x + threadIdx.x; i < (WMAT_N / 4);
       i += gridDim.x * blockDim.x) {
    float4 v = w4[i];
    bf16x4 r;
    r[0] = (bfloat)(((double)fabsf(v.x) > thr) ? (v.x > 0.f ? 1.f : -1.f) : 0.f);
    r[1] = (bfloat)(((double)fabsf(v.y) > thr) ? (v.y > 0.f ? 1.f : -1.f) : 0.f);
    r[2] = (bfloat)(((double)fabsf(v.z) > thr) ? (v.z > 0.f ? 1.f : -1.f) : 0.f);
    r[3] = (bfloat)(((double)fabsf(v.w) > thr) ? (v.w > 0.f ? 1.f : -1.f) : 0.f);
    *(bf16x4*)&o[(size_t)i * 4] = r;
  }
}

// -------- fused q/k/v projection v3: A fragments DIRECT from global.
// qkv was LDS-read-bound (24 b128/wave/step = 3456 cyc/CU vs 930 MFMA).
// Each lane's MFMA A-fragment is 8 contiguous fp32 in global: load 2 float4,
// cvt to hi/lo bf16x8 in-register -> A never touches LDS (-16 reads, -12
// ds_writes per wave/step). W double-buffered in LDS, prefetched right after
// the step-top barrier (full MFMA phase of latency cover). Single barrier +
// vmcnt(0) per step. XCD-grouped grid: 768 = 8 xcd x 12 slices x 8 xblk.
// V^T written with per-64-key bit-permutation pos(kk)=[b5][b3][b2][b4][b1][b0].
__global__ __launch_bounds__(256) void qkv_gemm(
    const float* __restrict__ xq, const float* __restrict__ xk,
    const float* __restrict__ xv, const bfloat* __restrict__ wqt,
    const bfloat* __restrict__ wkt, const bfloat* __restrict__ wvt,
    bfloat* __restrict__ qmh, bfloat* __restrict__ qml,
    bfloat* __restrict__ kmh, bfloat* __restrict__ kml, bfloat* __restrict__ vtr) {
  constexpr int K = D;
  constexpr int N = D;
  __shared__ __align__(16) bfloat Ws[2][128 * 64];  // 32 KB double buffer

  // XCD-grouped decomposition (bijective): bid -> (z, by, bx)
  const int bid = blockIdx.x;
  const int xcd = bid & 7;
  const int i6 = bid >> 3;                 // [0,96)
  const int slice = xcd * 12 + (i6 >> 3);  // [0,96) = 32 y x 3 z
  const int bx = i6 & 7;
  const int z = slice >> 5;
  const int by = slice & 31;

  const float* Af;
  const bfloat* Wm;
  bfloat *Oh = nullptr, *Ol = nullptr;
  float scale = 1.f;
  bool split;
  if (z == 0) {
    Af = xq; Wm = wqt; Oh = qmh; Ol = qml;
    scale = 0.18033688f;  // 1/sqrt(64) * log2(e), folded out of flash
    split = true;
  } else if (z == 1) {
    Af = xk; Wm = wkt; Oh = kmh; Ol = kml; split = true;
  } else {
    Af = xv; Wm = wvt; split = false;
  }

  const int t = threadIdx.x;
  const int w = t >> 6, lane = t & 63;
  const int quad = lane >> 4, l16 = lane & 15;
  const int wm = w >> 1, wn = w & 1;
  const int m0 = by * 128, n0 = bx * 128;

  f32x4 acc[4][4] = {};

  const int srr = lane >> 3;        // W staging row within 8-row group
  const int spc = lane & 7;         // physical chunk
  const int cl8 = (spc ^ srr) * 8;  // pre-swizzled source chunk (elems)

  // per-lane A fragment base pointers (one per mt)
  const float* aB[4];
#pragma unroll
  for (int mt = 0; mt < 4; mt++)
    aB[mt] = Af + (size_t)(m0 + wm * 64 + mt * 16 + l16) * K + quad * 8;

  // W staging sources (per g)
  const bfloat* wB[4];
#pragma unroll
  for (int g = 0; g < 4; g++)
    wB[g] = Wm + (size_t)(n0 + w * 32 + g * 8 + srr) * K + cl8;

  // ---- prologue: W(0) -> Ws[0]; A(0) -> registers ----
#pragma unroll
  for (int g = 0; g < 4; g++) gl_lds16(wB[g], &Ws[0][(w * 32 + g * 8) * 64]);
  float4 fa[4][2][2];  // [mt][kidx][half]
#pragma unroll
  for (int mt = 0; mt < 4; mt++)
#pragma unroll
    for (int kidx = 0; kidx < 2; kidx++) {
      fa[mt][kidx][0] = *(const float4*)(aB[mt] + kidx * 32);
      fa[mt][kidx][1] = *(const float4*)(aB[mt] + kidx * 32 + 4);
    }

  for (int kk = 0; kk < K; kk += 64) {
    const int cur = (kk >> 6) & 1;
    // everything outstanding (W(t) DMA + A(t) loads) landed; sync buffers
    asm volatile("s_waitcnt vmcnt(0)" ::: "memory");
    __builtin_amdgcn_s_barrier();
    asm volatile("" ::: "memory");

    // prefetch W(t+1) into the other buffer (drained at next step's top)
    if (kk + 64 < K) {
#pragma unroll
      for (int g = 0; g < 4; g++)
        gl_lds16(wB[g] + kk + 64, &Ws[1 - cur][(w * 32 + g * 8) * 64]);
    }

    const bfloat* wsc = &Ws[cur][0];
#pragma unroll
    for (int kidx = 0; kidx < 2; kidx++) {
      // cvt A(t) kidx-half -> hi/lo fragments (in-register, no LDS)
      bf16x8 fh[4], fl[4];
#pragma unroll
      for (int mt = 0; mt < 4; mt++) {
        float f[8] = {fa[mt][kidx][0].x, fa[mt][kidx][0].y, fa[mt][kidx][0].z,
                      fa[mt][kidx][0].w, fa[mt][kidx][1].x, fa[mt][kidx][1].y,
                      fa[mt][kidx][1].z, fa[mt][kidx][1].w};
#pragma unroll
        for (int j = 0; j < 8; j++) fh[mt][j] = (bfloat)f[j];
        if (split) {
#pragma unroll
          for (int j = 0; j < 8; j++) fl[mt][j] = (bfloat)(f[j] - (float)fh[mt][j]);
        }
      }
      // after the last cvt consumed fa, issue A(t+1) into the same regs
      if (kidx == 1 && kk + 64 < K) {
#pragma unroll
        for (int mt = 0; mt < 4; mt++)
#pragma unroll
          for (int kx = 0; kx < 2; kx++) {
            fa[mt][kx][0] = *(const float4*)(aB[mt] + kk + 64 + kx * 32);
            fa[mt][kx][1] = *(const float4*)(aB[mt] + kk + 64 + kx * 32 + 4);
          }
      }
      // B fragments from LDS; hi then lo MFMAs (same accumulation order)
      bf16x8 bfrag[4];
#pragma unroll
      for (int nt = 0; nt < 4; nt++) {
        int r = wn * 64 + nt * 16 + l16;
        bfrag[nt] = *(const bf16x8*)&wsc[r * 64 + (((kidx * 4 + quad) ^ (r & 7)) * 8)];
      }
#pragma unroll
      for (int mt = 0; mt < 4; mt++)
#pragma unroll
        for (int nt = 0; nt < 4; nt++)
          acc[mt][nt] = MFMA_BF16(fh[mt], bfrag[nt], acc[mt][nt]);
      if (split) {
#pragma unroll
        for (int mt = 0; mt < 4; mt++)
#pragma unroll
          for (int nt = 0; nt < 4; nt++)
            acc[mt][nt] = MFMA_BF16(fl[mt], bfrag[nt], acc[mt][nt]);
      }
    }
  }

#pragma unroll
  for (int mt = 0; mt < 4; mt++) {
#pragma unroll
    for (int nt = 0; nt < 4; nt++) {
      const int row = m0 + wm * 64 + mt * 16 + quad * 4;
      const int col = n0 + wn * 64 + nt * 16 + l16;
      if (split) {
#pragma unroll
        for (int rg = 0; rg < 4; rg++) {
          float vv = acc[mt][nt][rg] * scale;
          size_t idx = (size_t)(row + rg) * N + col;
          bfloat hh = (bfloat)vv;
          Oh[idx] = hh;
          Ol[idx] = (bfloat)(vv - (float)hh);
        }
      } else {
        int bb = row >> 11, s = row & (S - 1);
        int kk6 = s & 63;
        int pos = (kk6 & 3) | (((kk6 >> 4) & 1) << 2) | (((kk6 >> 2) & 3) << 3) |
                  ((kk6 >> 5) << 5);
        int sp = (s & ~63) | pos;
        bf16x4 pk;
#pragma unroll
        for (int rg = 0; rg < 4; rg++) pk[rg] = (bfloat)acc[mt][nt][rg];
        *(bf16x4*)&vtr[(size_t)bb * D * S + (size_t)col * S + sp] = pk;
      }
    }
  }
}

// -------- W_O GEMM v2: 128x64 tile, BK=64 (proven R11, 269.2 us config).
// XCD-grouped: 512 = 8 xcd x 4 yrows x 16 xblk (x-blocks share A panel).
__global__ __launch_bounds__(256) void gemm_wo(const bfloat* __restrict__ A,
                                               const bfloat* __restrict__ Wm,
                                               float* __restrict__ Cf) {
  constexpr int K = D;
  constexpr int N = D;
  __shared__ __align__(16) bfloat As[128 * 64];  // 16 KB
  __shared__ __align__(16) bfloat Ws[64 * 64];   //  8 KB

  const int bid = blockIdx.x;
  const int xcd = bid & 7;
  const int i6 = bid >> 3;               // [0,64)
  const int by = xcd * 4 + (i6 >> 4);    // [0,32)
  const int bx = i6 & 15;                // [0,16)

  const int t = threadIdx.x;
  const int w = t >> 6, lane = t & 63;
  const int quad = lane >> 4, l16 = lane & 15;
  const int wm = w >> 1, wn = w & 1;
  const int m0 = by * 128, n0 = bx * 64;

  f32x4 acc[4][2] = {};

  const int srr = lane >> 3;  // row within 8-row group
  const int spc = lane & 7;   // physical chunk
  const int cl8 = (spc ^ srr) * 8;

  for (int kk = 0; kk < K; kk += 64) {
    // A: 128 rows (4 gl_lds16/thread), W: 64 rows (2 gl_lds16/thread)
#pragma unroll
    for (int g = 0; g < 4; g++) {
      int rb = w * 32 + g * 8;
      gl_lds16(A + (size_t)(m0 + rb + srr) * K + kk + cl8, As + rb * 64);
    }
#pragma unroll
    for (int g = 0; g < 2; g++) {
      int rb = w * 16 + g * 8;
      gl_lds16(Wm + (size_t)(n0 + rb + srr) * K + kk + cl8, Ws + rb * 64);
    }
    __syncthreads();

#pragma unroll
    for (int kidx = 0; kidx < 2; kidx++) {
      bf16x8 af[4], bfr[2];
#pragma unroll
      for (int nt = 0; nt < 2; nt++) {
        int r = wn * 32 + nt * 16 + l16;
        bfr[nt] = *(const bf16x8*)&Ws[r * 64 + (((kidx * 4 + quad) ^ (r & 7)) * 8)];
      }
#pragma unroll
      for (int mt = 0; mt < 4; mt++) {
        int r = wm * 64 + mt * 16 + l16;
        af[mt] = *(const bf16x8*)&As[r * 64 + (((kidx * 4 + quad) ^ (r & 7)) * 8)];
      }
#pragma unroll
      for (int mt = 0; mt < 4; mt++)
#pragma unroll
        for (int nt = 0; nt < 2; nt++)
          acc[mt][nt] = MFMA_BF16(af[mt], bfr[nt], acc[mt][nt]);
    }
    __syncthreads();
  }

#pragma unroll
  for (int mt = 0; mt < 4; mt++) {
#pragma unroll
    for (int nt = 0; nt < 2; nt++) {
      const int row = m0 + wm * 64 + mt * 16 + quad * 4;
      const int col = n0 + wn * 32 + nt * 16 + l16;
#pragma unroll
      for (int rg = 0; rg < 4; rg++) Cf[(size_t)(row + rg) * N + col] = acc[mt][nt][rg];
    }
  }
}

// ---------------- flash attention v9 (proven 92 us): L2-resident K/V ------
// 512 blocks x 8 waves, 16 q-rows/wave, XCD-grouped block remap, K double-
// buffered with counted vmcnt, in-register P via permuted V^T, defer-max.
__global__ __launch_bounds__(512) void flash_kernel(
    const bfloat* __restrict__ qh, const bfloat* __restrict__ ql,
    const bfloat* __restrict__ kh, const bfloat* __restrict__ kl,
    const bfloat* __restrict__ vt, bfloat* __restrict__ outp) {
  __shared__ __align__(16) bfloat SM[20480];

  const int tid = threadIdx.x;
  const int w = tid >> 6, lane = tid & 63;
  const int quad = lane >> 4, l16 = lane & 15;

  // XCD-grouped decomposition: 512 blocks, xcd = blk&7 (dispatch round-robin);
  // each XCD gets (b,h) groups [4*xcd, 4*xcd+4) x 16 q-blocks.
  const int blk = blockIdx.x;
  const int xcd = blk & 7, slot = blk >> 3;
  const int g = xcd * 4 + (slot >> 4);
  const int h = g & 15, b = g >> 4;
  const int q0 = (slot & 15) * 128;

  const size_t base = (size_t)b * S * D + (size_t)h * DH;       // [b][s][n]
  const size_t vbase = (size_t)b * D * S + (size_t)h * DH * S;  // [b][n][s]

  const int ssr = lane >> 3;
  const int spc = lane & 7;
  const int c8 = (spc ^ ssr) * 8;  // pre-swizzled source chunk (row&7 == ssr)
  const int stKV = w * 512;        // wave-uniform K/V staging dest (8 rows)

  // staging pointers
  const bfloat* pKh = kh + base + (size_t)(w * 8 + ssr) * D + c8;
  const bfloat* pKl = kl + base + (size_t)(w * 8 + ssr) * D + c8;
  const bfloat* pV = vt + vbase + (size_t)(w * 8 + ssr) * S + c8;

  bf16x8 ones;
#pragma unroll
  for (int j = 0; j < 8; j++) ones[j] = (bfloat)1.f;

  // ---- prologue: Qh -> SM[0..8192), Ql -> SM[8192..16384); frags to regs --
  {
    const bfloat* pQh = qh + base + (size_t)(q0 + w * 16 + ssr) * D + c8;
    const bfloat* pQl = ql + base + (size_t)(q0 + w * 16 + ssr) * D + c8;
    gl_lds16(pQh, SM + w * 1024);
    gl_lds16(pQh + 8 * D, SM + w * 1024 + 512);
    gl_lds16(pQl, SM + 8192 + w * 1024);
    gl_lds16(pQl + 8 * D, SM + 8192 + w * 1024 + 512);
  }
  asm volatile("s_waitcnt vmcnt(0)" ::: "memory");
  __builtin_amdgcn_s_barrier();
  asm volatile("" ::: "memory");

  const int fo0 = l16 * 64 + ((quad ^ (l16 & 7)) * 8);  // lane frag offset
  const int fo4 = fo0 ^ 32;                             // s2=1 chunk
  const int fq = w * 1024;                              // wave's Q rows

  bf16x8 qhf0 = *(const bf16x8*)&SM[fq + fo0];
  bf16x8 qhf1 = *(const bf16x8*)&SM[fq + fo4];
  bf16x8 qlf0 = *(const bf16x8*)&SM[8192 + fq + fo0];
  bf16x8 qlf1 = *(const bf16x8*)&SM[8192 + fq + fo4];
  asm volatile("s_waitcnt lgkmcnt(0)" ::: "memory");
  __builtin_amdgcn_s_barrier();  // all waves done reading Q before K staging
  asm volatile("" ::: "memory");

  // K(0) -> kbuf0
  gl_lds16(pKh, SM + 0 + stKV);
  gl_lds16(pKl, SM + 4096 + stKV);
  pKh += 64 * D;
  pKl += 64 * D;
  asm volatile("s_waitcnt vmcnt(0)" ::: "memory");

  f32x4 Oa[4] = {};  // O^T: elem rg -> dim=mt*16+quad*4+rg, qrow=l16
  f32x4 La = {};     // all regs equal: sum_k P (per qrow=l16)
  float m_i = -3.0e38f;
  constexpr int NT = S / 64;

  for (int t = 0; t < NT; ++t) {
    __builtin_amdgcn_s_barrier();  // barrier A (K(t) visible; V readers done)
    asm volatile("" ::: "memory");
    const int cur = (t & 1) * 8192;
    const int nxt = 8192 - cur;

    // stage V(t) + K(t+1); they fly across the compute below
    gl_lds16(pV, SM + 16384 + stKV);
    pV += 64;
    if (t < NT - 1) {
      gl_lds16(pKh, SM + nxt + stKV);
      gl_lds16(pKl, SM + nxt + 4096 + stKV);
      pKh += 64 * D;
      pKl += 64 * D;
    }

    // ---- QK: S^T = Kh*Qh + Kl*Qh + Kh*Ql (pre-scaled, log2 domain) ----
    f32x4 sf[4];
    __builtin_amdgcn_s_setprio(1);
#pragma unroll
    for (int mt = 0; mt < 4; mt++) {
      f32x4 a = {};
      bf16x8 bh0 = *(const bf16x8*)&SM[cur + fo0 + mt * 1024];
      bf16x8 bl0 = *(const bf16x8*)&SM[cur + 4096 + fo0 + mt * 1024];
      bf16x8 bh1 = *(const bf16x8*)&SM[cur + fo4 + mt * 1024];
      bf16x8 bl1 = *(const bf16x8*)&SM[cur + 4096 + fo4 + mt * 1024];
      a = MFMA_BF16(bh0, qhf0, a);
      a = MFMA_BF16(bl0, qhf0, a);
      a = MFMA_BF16(bh0, qlf0, a);
      a = MFMA_BF16(bh1, qhf1, a);
      a = MFMA_BF16(bl1, qhf1, a);
      a = MFMA_BF16(bh1, qlf1, a);
      sf[mt] = a;
    }
    __builtin_amdgcn_s_setprio(0);

    // ---- online softmax, tree max + defer-max threshold (T13) ----
    float t0 = fmaxf(fmaxf(sf[0][0], sf[0][1]), fmaxf(sf[0][2], sf[0][3]));
    float t1 = fmaxf(fmaxf(sf[1][0], sf[1][1]), fmaxf(sf[1][2], sf[1][3]));
    float t2 = fmaxf(fmaxf(sf[2][0], sf[2][1]), fmaxf(sf[2][2], sf[2][3]));
    float t3 = fmaxf(fmaxf(sf[3][0], sf[3][1]), fmaxf(sf[3][2], sf[3][3]));
    float mm = fmaxf(fmaxf(t0, t1), fmaxf(t2, t3));
    mm = fmaxf(mm, __shfl_xor(mm, 16, 64));
    mm = fmaxf(mm, __shfl_xor(mm, 32, 64));
    if (__ballot(mm > m_i + 8.0f)) {  // rescale only on >8 (log2) growth
      float mnew = fmaxf(m_i, mm);
      float alpha = exp2f(m_i - mnew);
      m_i = mnew;
#pragma unroll
      for (int mt = 0; mt < 4; mt++) Oa[mt] *= alpha;
      La *= alpha;
    }
#pragma unroll
    for (int mt = 0; mt < 4; mt++)
#pragma unroll
      for (int rg = 0; rg < 4; rg++) sf[mt][rg] = exp2f(sf[mt][rg] - m_i);

    // mid wait: V(t) landed (K(t+1)'s 2 loads stay in flight)
    if (t < NT - 1)
      asm volatile("s_waitcnt vmcnt(2)" ::: "memory");
    else
      asm volatile("s_waitcnt vmcnt(0)" ::: "memory");
    __builtin_amdgcn_s_barrier();  // barrier B: V(t) visible to all
    asm volatile("" ::: "memory");

    // ---- PV: O^T += V^T * P^T ; La += ones * P^T (P from registers) ----
    __builtin_amdgcn_s_setprio(1);
#pragma unroll
    for (int kp = 0; kp < 2; kp++) {
      bf16x8 pb8;
#pragma unroll
      for (int rg = 0; rg < 4; rg++) {
        pb8[rg] = (bfloat)sf[2 * kp][rg];
        pb8[4 + rg] = (bfloat)sf[2 * kp + 1][rg];
      }
      La = MFMA_BF16(ones, pb8, La);
      const int fv = kp ? fo4 : fo0;
#pragma unroll
      for (int mt = 0; mt < 4; mt++) {
        bf16x8 va = *(const bf16x8*)&SM[16384 + fv + mt * 1024];
        Oa[mt] = MFMA_BF16(va, pb8, Oa[mt]);
      }
    }
    __builtin_amdgcn_s_setprio(0);
    // end wait: K(t+1) landed (issued a full phase ago -> ~free)
    asm volatile("s_waitcnt vmcnt(0)" ::: "memory");
  }

  // epilogue: lane owns qrow=l16; 4 consecutive dims per mt -> b64 stores
  float inv = 1.0f / La[0];
  const int qrow = q0 + w * 16 + l16;
#pragma unroll
  for (int mt = 0; mt < 4; mt++) {
    bf16x4 ov;
#pragma unroll
    for (int rg = 0; rg < 4; rg++) ov[rg] = (bfloat)(Oa[mt][rg] * inv);
    *(bf16x4*)&outp[base + (size_t)qrow * D + mt * 16 + quad * 4] = ov;
  }
}

extern "C" void kernel_launch(void* const* d_in, const int* in_sizes, int n_in,
                              void* d_out, int out_size, void* d_ws, size_t ws_size,
                              hipStream_t stream) {
  const float* q_in = (const float*)d_in[0];
  const float* k_in = (const float*)d_in[1];
  const float* v_in = (const float*)d_in[2];
  const float* wq = (const float*)d_in[3];
  const float* wk = (const float*)d_in[4];
  const float* wv = (const float*)d_in[5];
  const float* wo = (const float*)d_in[6];
  float* outp = (float*)d_out;
  char* ws = (char*)d_ws;

  constexpr size_t WBYTES = (size_t)WMAT_N * 2;
  constexpr size_t XBYTES = (size_t)M * D * 2;
  size_t off = 0;
  double* sums = (double*)(ws + off); off += 256;
  bfloat* wqt = (bfloat*)(ws + off); off += WBYTES;
  bfloat* wkt = (bfloat*)(ws + off); off += WBYTES;
  bfloat* wvt = (bfloat*)(ws + off); off += WBYTES;
  bfloat* wot = (bfloat*)(ws + off); off += WBYTES;
  bfloat* qmh = (bfloat*)(ws + off); off += XBYTES;
  bfloat* qml = (bfloat*)(ws + off); off += XBYTES;
  bfloat* kmh = (bfloat*)(ws + off); off += XBYTES;
  bfloat* kml = (bfloat*)(ws + off); off += XBYTES;
  bfloat* vtr = (bfloat*)(ws + off); off += XBYTES;  // V^T [B][D][S], key-permuted
  bfloat* attn = (bfloat*)(ws + off); off += XBYTES;

  hipMemsetAsync(sums, 0, 4 * sizeof(double), stream);
  prep_kernel<<<dim3(256, 4), 256, 0, stream>>>(wq, wk, wv, wo, sums);
  tern_kernel<<<dim3(128, 4), 256, 0, stream>>>(wq, wk, wv, wo, wqt, wkt, wvt, wot, sums);
  qkv_gemm<<<768, 256, 0, stream>>>(
      q_in, k_in, v_in, wqt, wkt, wvt, qmh, qml, kmh, kml, vtr);
  flash_kernel<<<512, 512, 0, stream>>>(qmh, qml, kmh, kml, vtr, attn);
  gemm_wo<<<512, 256, 0, stream>>>(attn, wot, outp);
}

// Round 14
// 265.338 us; speedup vs baseline: 1.3018x; 1.3018x over previous
//
#include <hip/hip_runtime.h>
#include <cstdint>
#include <cstddef>

typedef __bf16 bfloat;
typedef __bf16 bf16x8 __attribute__((ext_vector_type(8)));
typedef __bf16 bf16x4 __attribute__((ext_vector_type(4)));
typedef float  f32x4  __attribute__((ext_vector_type(4)));

static constexpr int D  = 1024;
static constexpr int S  = 2048;
static constexpr int B  = 2;
static constexpr int H  = 16;
static constexpr int DH = 64;
static constexpr int M  = B * S;
static constexpr int WMAT_N = 1024 * 1024;

#define MFMA_BF16(a, b, c) __builtin_amdgcn_mfma_f32_16x16x32_bf16((a), (b), (c), 0, 0, 0)

__device__ __forceinline__ void gl_lds16(const void* g, void* l) {
  __builtin_amdgcn_global_load_lds(
      (const __attribute__((address_space(1))) void*)g,
      (__attribute__((address_space(3))) void*)l, 16, 0, 0);
}

// ---- prep: f64 abs-sum of weight y ----
__global__ void prep_kernel(const float* __restrict__ w0, const float* __restrict__ w1,
                            const float* __restrict__ w2, const float* __restrict__ w3,
                            double* __restrict__ sums) {
  const int y = blockIdx.y;
  const float* w = (y == 0) ? w0 : (y == 1) ? w1 : (y == 2) ? w2 : w3;
  const float4* w4 = (const float4*)w;
  double s = 0.0;
  for (int i = blockIdx.x * blockDim.x + threadIdx.x; i < (WMAT_N / 4);
       i += gridDim.x * blockDim.x) {
    float4 v = w4[i];
    s += (double)fabsf(v.x) + (double)fabsf(v.y) + (double)fabsf(v.z) + (double)fabsf(v.w);
  }
  for (int off = 1; off < 64; off <<= 1) s += __shfl_xor(s, off, 64);
  __shared__ double ps[4];
  if ((threadIdx.x & 63) == 0) ps[threadIdx.x >> 6] = s;
  __syncthreads();
  if (threadIdx.x == 0) atomicAdd(&sums[y], ps[0] + ps[1] + ps[2] + ps[3]);
}

// ---------------- ternarize -> bf16 ----------------
__global__ void tern_kernel(const float* __restrict__ w0, const float* __restrict__ w1,
                            const float* __restrict__ w2, const float* __restrict__ w3,
                            bfloat* __restrict__ o0, bfloat* __restrict__ o1,
                            bfloat* __restrict__ o2, bfloat* __restrict__ o3,
                            const double* __restrict__ sums) {
  int z = blockIdx.y;
  const float* w = (z == 0) ? w0 : (z == 1) ? w1 : (z == 2) ? w2 : w3;
  bfloat* o = (z == 0) ? o0 : (z == 1) ? o1 : (z == 2) ? o2 : o3;
  double thr = sums[z] * (1.0 / (double)WMAT_N);
  const float4* w4 = (const float4*)w;
  for (int i = blockIdx.x * blockDim.x + threadIdx.x; i < (WMAT_N / 4);
       i += gridDim.x * blockDim.x) {
    float4 v = w4[i];
    bf16x4 r;
    r[0] = (bfloat)(((double)fabsf(v.x) > thr) ? (v.x > 0.f ? 1.f : -1.f) : 0.f);
    r[1] = (bfloat)(((double)fabsf(v.y) > thr) ? (v.y > 0.f ? 1.f : -1.f) : 0.f);
    r[2] = (bfloat)(((double)fabsf(v.z) > thr) ? (v.z > 0.f ? 1.f : -1.f) : 0.f);
    r[3] = (bfloat)(((double)fabsf(v.w) > thr) ? (v.w > 0.f ? 1.f : -1.f) : 0.f);
    *(bf16x4*)&o[(size_t)i * 4] = r;
  }
}

// -------- fused q/k/v projection (R10's verified variant): 128x128 tile,
// BK=64, FULLY reg-pipelined. Both A(t+1) (fp32, 32 VGPR) and W(t+1) (bf16,
// 16 VGPR) prefetched into held registers right after the staging barrier of
// step t via COALESCED row-segment loads (8 lanes x 16B contiguous per row);
// cvt+ds_write at top of t+1 (T14). No gl_lds16 here -> staging barrier needs
// only lgkmcnt(0); ZERO vmcnt drains in the K-loop.
// XCD-grouped 1-D grid (T1): 768 = 8 xcd x 12 slices x 8 xblk.
// V^T written with per-64-key bit-permutation pos(kk)=[b5][b3][b2][b4][b1][b0].
__global__ __launch_bounds__(256) void qkv_gemm(
    const float* __restrict__ xq, const float* __restrict__ xk,
    const float* __restrict__ xv, const bfloat* __restrict__ wqt,
    const bfloat* __restrict__ wkt, const bfloat* __restrict__ wvt,
    bfloat* __restrict__ qmh, bfloat* __restrict__ qml,
    bfloat* __restrict__ kmh, bfloat* __restrict__ kml, bfloat* __restrict__ vtr) {
  constexpr int K = D;
  constexpr int N = D;
  __shared__ __align__(16) bfloat As0[128 * 64];
  __shared__ __align__(16) bfloat As1[128 * 64];
  __shared__ __align__(16) bfloat Ws[128 * 64];

  // XCD-grouped decomposition (bijective): bid -> (z, by, bx)
  const int bid = blockIdx.x;
  const int xcd = bid & 7;
  const int i6 = bid >> 3;                 // [0,96)
  const int slice = xcd * 12 + (i6 >> 3);  // [0,96) = 32 y x 3 z
  const int bx = i6 & 7;
  const int z = slice >> 5;
  const int by = slice & 31;

  const float* Af;
  const bfloat* Wm;
  bfloat *Oh = nullptr, *Ol = nullptr;
  float scale = 1.f;
  bool split;
  if (z == 0) {
    Af = xq; Wm = wqt; Oh = qmh; Ol = qml;
    scale = 0.18033688f;  // 1/sqrt(64) * log2(e), folded out of flash
    split = true;
  } else if (z == 1) {
    Af = xk; Wm = wkt; Oh = kmh; Ol = kml; split = true;
  } else {
    Af = xv; Wm = wvt; split = false;
  }

  const int t = threadIdx.x;
  const int w = t >> 6, lane = t & 63;
  const int quad = lane >> 4, l16 = lane & 15;
  const int wm = w >> 1, wn = w & 1;
  const int m0 = by * 128, n0 = bx * 128;

  f32x4 acc[4][4] = {};

  const int srr = lane >> 3;  // row within 8-row group (== row&7 for our rows)
  const int spc = lane & 7;   // physical chunk
  const int cl8 = (spc ^ srr) * 8;  // logical chunk offset (elems)

  // per-lane A and W source pointers (row = w*32 + g*8 + srr)
  const float* aSrc[4];
  const bfloat* wSrc[4];
#pragma unroll
  for (int g = 0; g < 4; g++) {
    aSrc[g] = Af + (size_t)(m0 + w * 32 + g * 8 + srr) * K + cl8;
    wSrc[g] = Wm + (size_t)(n0 + w * 32 + g * 8 + srr) * K + cl8;
  }

  // prologue: load A(0), W(0) into held registers
  float4 fa[4][2];
  bf16x8 fw[4];
#pragma unroll
  for (int g = 0; g < 4; g++) {
    fa[g][0] = *(const float4*)(aSrc[g]);
    fa[g][1] = *(const float4*)(aSrc[g] + 4);
    fw[g] = *(const bf16x8*)(wSrc[g]);
  }

  for (int kk = 0; kk < K; kk += 64) {
    // write W(t) + cvt/write A(t) from held regs (compiler waits the loads)
#pragma unroll
    for (int g = 0; g < 4; g++) {
      int row = w * 32 + g * 8 + srr;
      const int da = row * 64 + spc * 8;
      *(bf16x8*)&Ws[da] = fw[g];
      float f[8] = {fa[g][0].x, fa[g][0].y, fa[g][0].z, fa[g][0].w,
                    fa[g][1].x, fa[g][1].y, fa[g][1].z, fa[g][1].w};
      bf16x8 hh;
#pragma unroll
      for (int j = 0; j < 8; j++) hh[j] = (bfloat)f[j];
      *(bf16x8*)&As0[da] = hh;
      if (split) {
        bf16x8 ll;
#pragma unroll
        for (int j = 0; j < 8; j++) ll[j] = (bfloat)(f[j] - (float)hh[j]);
        *(bf16x8*)&As1[da] = ll;
      }
    }
    // staging barrier: ds_writes visible; no vm ops outstanding here
    asm volatile("s_waitcnt lgkmcnt(0)" ::: "memory");
    __builtin_amdgcn_s_barrier();
    asm volatile("" ::: "memory");

    // issue A(t+1)+W(t+1) prefetch; flies across MFMA phase + end barrier
    if (kk + 64 < K) {
#pragma unroll
      for (int g = 0; g < 4; g++) {
        fa[g][0] = *(const float4*)(aSrc[g] + kk + 64);
        fa[g][1] = *(const float4*)(aSrc[g] + kk + 64 + 4);
        fw[g] = *(const bf16x8*)(wSrc[g] + kk + 64);
      }
    }

#pragma unroll
    for (int kidx = 0; kidx < 2; kidx++) {
      bf16x8 bfrag[4], afrag[4];
#pragma unroll
      for (int nt = 0; nt < 4; nt++) {
        int r = wn * 64 + nt * 16 + l16;
        bfrag[nt] = *(const bf16x8*)&Ws[r * 64 + (((kidx * 4 + quad) ^ (r & 7)) * 8)];
      }
#pragma unroll
      for (int mt = 0; mt < 4; mt++) {
        int r = wm * 64 + mt * 16 + l16;
        afrag[mt] = *(const bf16x8*)&As0[r * 64 + (((kidx * 4 + quad) ^ (r & 7)) * 8)];
      }
#pragma unroll
      for (int mt = 0; mt < 4; mt++)
#pragma unroll
        for (int nt = 0; nt < 4; nt++)
          acc[mt][nt] = MFMA_BF16(afrag[mt], bfrag[nt], acc[mt][nt]);
      if (split) {
#pragma unroll
        for (int mt = 0; mt < 4; mt++) {
          int r = wm * 64 + mt * 16 + l16;
          afrag[mt] = *(const bf16x8*)&As1[r * 64 + (((kidx * 4 + quad) ^ (r & 7)) * 8)];
        }
#pragma unroll
        for (int mt = 0; mt < 4; mt++)
#pragma unroll
          for (int nt = 0; nt < 4; nt++)
            acc[mt][nt] = MFMA_BF16(afrag[mt], bfrag[nt], acc[mt][nt]);
      }
    }
    // end-of-step barrier: NO waitcnt (keeps the prefetch in flight).
    asm volatile("" ::: "memory");
    __builtin_amdgcn_s_barrier();
    asm volatile("" ::: "memory");
  }

#pragma unroll
  for (int mt = 0; mt < 4; mt++) {
#pragma unroll
    for (int nt = 0; nt < 4; nt++) {
      const int row = m0 + wm * 64 + mt * 16 + quad * 4;
      const int col = n0 + wn * 64 + nt * 16 + l16;
      if (split) {
#pragma unroll
        for (int rg = 0; rg < 4; rg++) {
          float vv = acc[mt][nt][rg] * scale;
          size_t idx = (size_t)(row + rg) * N + col;
          bfloat hh = (bfloat)vv;
          Oh[idx] = hh;
          Ol[idx] = (bfloat)(vv - (float)hh);
        }
      } else {
        int bb = row >> 11, s = row & (S - 1);
        int kk6 = s & 63;
        int pos = (kk6 & 3) | (((kk6 >> 4) & 1) << 2) | (((kk6 >> 2) & 3) << 3) |
                  ((kk6 >> 5) << 5);
        int sp = (s & ~63) | pos;
        bf16x4 pk;
#pragma unroll
        for (int rg = 0; rg < 4; rg++) pk[rg] = (bfloat)acc[mt][nt][rg];
        *(bf16x4*)&vtr[(size_t)bb * D * S + (size_t)col * S + sp] = pk;
      }
    }
  }
}

// -------- W_O GEMM v2: 128x64 tile, BK=64 (proven R11 config).
// XCD-grouped: 512 = 8 xcd x 4 yrows x 16 xblk (x-blocks share A panel).
__global__ __launch_bounds__(256) void gemm_wo(const bfloat* __restrict__ A,
                                               const bfloat* __restrict__ Wm,
                                               float* __restrict__ Cf) {
  constexpr int K = D;
  constexpr int N = D;
  __shared__ __align__(16) bfloat As[128 * 64];  // 16 KB
  __shared__ __align__(16) bfloat Ws[64 * 64];   //  8 KB

  const int bid = blockIdx.x;
  const int xcd = bid & 7;
  const int i6 = bid >> 3;               // [0,64)
  const int by = xcd * 4 + (i6 >> 4);    // [0,32)
  const int bx = i6 & 15;                // [0,16)

  const int t = threadIdx.x;
  const int w = t >> 6, lane = t & 63;
  const int quad = lane >> 4, l16 = lane & 15;
  const int wm = w >> 1, wn = w & 1;
  const int m0 = by * 128, n0 = bx * 64;

  f32x4 acc[4][2] = {};

  const int srr = lane >> 3;  // row within 8-row group
  const int spc = lane & 7;   // physical chunk
  const int cl8 = (spc ^ srr) * 8;

  for (int kk = 0; kk < K; kk += 64) {
    // A: 128 rows (4 gl_lds16/thread), W: 64 rows (2 gl_lds16/thread)
#pragma unroll
    for (int g = 0; g < 4; g++) {
      int rb = w * 32 + g * 8;
      gl_lds16(A + (size_t)(m0 + rb + srr) * K + kk + cl8, As + rb * 64);
    }
#pragma unroll
    for (int g = 0; g < 2; g++) {
      int rb = w * 16 + g * 8;
      gl_lds16(Wm + (size_t)(n0 + rb + srr) * K + kk + cl8, Ws + rb * 64);
    }
    __syncthreads();

#pragma unroll
    for (int kidx = 0; kidx < 2; kidx++) {
      bf16x8 af[4], bfr[2];
#pragma unroll
      for (int nt = 0; nt < 2; nt++) {
        int r = wn * 32 + nt * 16 + l16;
        bfr[nt] = *(const bf16x8*)&Ws[r * 64 + (((kidx * 4 + quad) ^ (r & 7)) * 8)];
      }
#pragma unroll
      for (int mt = 0; mt < 4; mt++) {
        int r = wm * 64 + mt * 16 + l16;
        af[mt] = *(const bf16x8*)&As[r * 64 + (((kidx * 4 + quad) ^ (r & 7)) * 8)];
      }
#pragma unroll
      for (int mt = 0; mt < 4; mt++)
#pragma unroll
        for (int nt = 0; nt < 2; nt++)
          acc[mt][nt] = MFMA_BF16(af[mt], bfr[nt], acc[mt][nt]);
    }
    __syncthreads();
  }

#pragma unroll
  for (int mt = 0; mt < 4; mt++) {
#pragma unroll
    for (int nt = 0; nt < 2; nt++) {
      const int row = m0 + wm * 64 + mt * 16 + quad * 4;
      const int col = n0 + wn * 32 + nt * 16 + l16;
#pragma unroll
      for (int rg = 0; rg < 4; rg++) Cf[(size_t)(row + rg) * N + col] = acc[mt][nt][rg];
    }
  }
}

// ---------------- flash attention v9 (proven 92 us): L2-resident K/V ------
// 512 blocks x 8 waves, 16 q-rows/wave, XCD-grouped block remap, K double-
// buffered with counted vmcnt, in-register P via permuted V^T, defer-max.
__global__ __launch_bounds__(512) void flash_kernel(
    const bfloat* __restrict__ qh, const bfloat* __restrict__ ql,
    const bfloat* __restrict__ kh, const bfloat* __restrict__ kl,
    const bfloat* __restrict__ vt, bfloat* __restrict__ outp) {
  __shared__ __align__(16) bfloat SM[20480];

  const int tid = threadIdx.x;
  const int w = tid >> 6, lane = tid & 63;
  const int quad = lane >> 4, l16 = lane & 15;

  // XCD-grouped decomposition: 512 blocks, xcd = blk&7 (dispatch round-robin);
  // each XCD gets (b,h) groups [4*xcd, 4*xcd+4) x 16 q-blocks.
  const int blk = blockIdx.x;
  const int xcd = blk & 7, slot = blk >> 3;
  const int g = xcd * 4 + (slot >> 4);
  const int h = g & 15, b = g >> 4;
  const int q0 = (slot & 15) * 128;

  const size_t base = (size_t)b * S * D + (size_t)h * DH;       // [b][s][n]
  const size_t vbase = (size_t)b * D * S + (size_t)h * DH * S;  // [b][n][s]

  const int ssr = lane >> 3;
  const int spc = lane & 7;
  const int c8 = (spc ^ ssr) * 8;  // pre-swizzled source chunk (row&7 == ssr)
  const int stKV = w * 512;        // wave-uniform K/V staging dest (8 rows)

  // staging pointers
  const bfloat* pKh = kh + base + (size_t)(w * 8 + ssr) * D + c8;
  const bfloat* pKl = kl + base + (size_t)(w * 8 + ssr) * D + c8;
  const bfloat* pV = vt + vbase + (size_t)(w * 8 + ssr) * S + c8;

  bf16x8 ones;
#pragma unroll
  for (int j = 0; j < 8; j++) ones[j] = (bfloat)1.f;

  // ---- prologue: Qh -> SM[0..8192), Ql -> SM[8192..16384); frags to regs --
  {
    const bfloat* pQh = qh + base + (size_t)(q0 + w * 16 + ssr) * D + c8;
    const bfloat* pQl = ql + base + (size_t)(q0 + w * 16 + ssr) * D + c8;
    gl_lds16(pQh, SM + w * 1024);
    gl_lds16(pQh + 8 * D, SM + w * 1024 + 512);
    gl_lds16(pQl, SM + 8192 + w * 1024);
    gl_lds16(pQl + 8 * D, SM + 8192 + w * 1024 + 512);
  }
  asm volatile("s_waitcnt vmcnt(0)" ::: "memory");
  __builtin_amdgcn_s_barrier();
  asm volatile("" ::: "memory");

  const int fo0 = l16 * 64 + ((quad ^ (l16 & 7)) * 8);  // lane frag offset
  const int fo4 = fo0 ^ 32;                             // s2=1 chunk
  const int fq = w * 1024;                              // wave's Q rows

  bf16x8 qhf0 = *(const bf16x8*)&SM[fq + fo0];
  bf16x8 qhf1 = *(const bf16x8*)&SM[fq + fo4];
  bf16x8 qlf0 = *(const bf16x8*)&SM[8192 + fq + fo0];
  bf16x8 qlf1 = *(const bf16x8*)&SM[8192 + fq + fo4];
  asm volatile("s_waitcnt lgkmcnt(0)" ::: "memory");
  __builtin_amdgcn_s_barrier();  // all waves done reading Q before K staging
  asm volatile("" ::: "memory");

  // K(0) -> kbuf0
  gl_lds16(pKh, SM + 0 + stKV);
  gl_lds16(pKl, SM + 4096 + stKV);
  pKh += 64 * D;
  pKl += 64 * D;
  asm volatile("s_waitcnt vmcnt(0)" ::: "memory");

  f32x4 Oa[4] = {};  // O^T: elem rg -> dim=mt*16+quad*4+rg, qrow=l16
  f32x4 La = {};     // all regs equal: sum_k P (per qrow=l16)
  float m_i = -3.0e38f;
  constexpr int NT = S / 64;

  for (int t = 0; t < NT; ++t) {
    __builtin_amdgcn_s_barrier();  // barrier A (K(t) visible; V readers done)
    asm volatile("" ::: "memory");
    const int cur = (t & 1) * 8192;
    const int nxt = 8192 - cur;

    // stage V(t) + K(t+1); they fly across the compute below
    gl_lds16(pV, SM + 16384 + stKV);
    pV += 64;
    if (t < NT - 1) {
      gl_lds16(pKh, SM + nxt + stKV);
      gl_lds16(pKl, SM + nxt + 4096 + stKV);
      pKh += 64 * D;
      pKl += 64 * D;
    }

    // ---- QK: S^T = Kh*Qh + Kl*Qh + Kh*Ql (pre-scaled, log2 domain) ----
    f32x4 sf[4];
    __builtin_amdgcn_s_setprio(1);
#pragma unroll
    for (int mt = 0; mt < 4; mt++) {
      f32x4 a = {};
      bf16x8 bh0 = *(const bf16x8*)&SM[cur + fo0 + mt * 1024];
      bf16x8 bl0 = *(const bf16x8*)&SM[cur + 4096 + fo0 + mt * 1024];
      bf16x8 bh1 = *(const bf16x8*)&SM[cur + fo4 + mt * 1024];
      bf16x8 bl1 = *(const bf16x8*)&SM[cur + 4096 + fo4 + mt * 1024];
      a = MFMA_BF16(bh0, qhf0, a);
      a = MFMA_BF16(bl0, qhf0, a);
      a = MFMA_BF16(bh0, qlf0, a);
      a = MFMA_BF16(bh1, qhf1, a);
      a = MFMA_BF16(bl1, qhf1, a);
      a = MFMA_BF16(bh1, qlf1, a);
      sf[mt] = a;
    }
    __builtin_amdgcn_s_setprio(0);

    // ---- online softmax, tree max + defer-max threshold (T13) ----
    float t0 = fmaxf(fmaxf(sf[0][0], sf[0][1]), fmaxf(sf[0][2], sf[0][3]));
    float t1 = fmaxf(fmaxf(sf[1][0], sf[1][1]), fmaxf(sf[1][2], sf[1][3]));
    float t2 = fmaxf(fmaxf(sf[2][0], sf[2][1]), fmaxf(sf[2][2], sf[2][3]));
    float t3 = fmaxf(fmaxf(sf[3][0], sf[3][1]), fmaxf(sf[3][2], sf[3][3]));
    float mm = fmaxf(fmaxf(t0, t1), fmaxf(t2, t3));
    mm = fmaxf(mm, __shfl_xor(mm, 16, 64));
    mm = fmaxf(mm, __shfl_xor(mm, 32, 64));
    if (__ballot(mm > m_i + 8.0f)) {  // rescale only on >8 (log2) growth
      float mnew = fmaxf(m_i, mm);
      float alpha = exp2f(m_i - mnew);
      m_i = mnew;
#pragma unroll
      for (int mt = 0; mt < 4; mt++) Oa[mt] *= alpha;
      La *= alpha;
    }
#pragma unroll
    for (int mt = 0; mt < 4; mt++)
#pragma unroll
      for (int rg = 0; rg < 4; rg++) sf[mt][rg] = exp2f(sf[mt][rg] - m_i);

    // mid wait: V(t) landed (K(t+1)'s 2 loads stay in flight)
    if (t < NT - 1)
      asm volatile("s_waitcnt vmcnt(2)" ::: "memory");
    else
      asm volatile("s_waitcnt vmcnt(0)" ::: "memory");
    __builtin_amdgcn_s_barrier();  // barrier B: V(t) visible to all
    asm volatile("" ::: "memory");

    // ---- PV: O^T += V^T * P^T ; La += ones * P^T (P from registers) ----
    __builtin_amdgcn_s_setprio(1);
#pragma unroll
    for (int kp = 0; kp < 2; kp++) {
      bf16x8 pb8;
#pragma unroll
      for (int rg = 0; rg < 4; rg++) {
        pb8[rg] = (bfloat)sf[2 * kp][rg];
        pb8[4 + rg] = (bfloat)sf[2 * kp + 1][rg];
      }
      La = MFMA_BF16(ones, pb8, La);
      const int fv = kp ? fo4 : fo0;
#pragma unroll
      for (int mt = 0; mt < 4; mt++) {
        bf16x8 va = *(const bf16x8*)&SM[16384 + fv + mt * 1024];
        Oa[mt] = MFMA_BF16(va, pb8, Oa[mt]);
      }
    }
    __builtin_amdgcn_s_setprio(0);
    // end wait: K(t+1) landed (issued a full phase ago -> ~free)
    asm volatile("s_waitcnt vmcnt(0)" ::: "memory");
  }

  // epilogue: lane owns qrow=l16; 4 consecutive dims per mt -> b64 stores
  float inv = 1.0f / La[0];
  const int qrow = q0 + w * 16 + l16;
#pragma unroll
  for (int mt = 0; mt < 4; mt++) {
    bf16x4 ov;
#pragma unroll
    for (int rg = 0; rg < 4; rg++) ov[rg] = (bfloat)(Oa[mt][rg] * inv);
    *(bf16x4*)&outp[base + (size_t)qrow * D + mt * 16 + quad * 4] = ov;
  }
}

extern "C" void kernel_launch(void* const* d_in, const int* in_sizes, int n_in,
                              void* d_out, int out_size, void* d_ws, size_t ws_size,
                              hipStream_t stream) {
  const float* q_in = (const float*)d_in[0];
  const float* k_in = (const float*)d_in[1];
  const float* v_in = (const float*)d_in[2];
  const float* wq = (const float*)d_in[3];
  const float* wk = (const float*)d_in[4];
  const float* wv = (const float*)d_in[5];
  const float* wo = (const float*)d_in[6];
  float* outp = (float*)d_out;
  char* ws = (char*)d_ws;

  constexpr size_t WBYTES = (size_t)WMAT_N * 2;
  constexpr size_t XBYTES = (size_t)M * D * 2;
  size_t off = 0;
  double* sums = (double*)(ws + off); off += 256;
  bfloat* wqt = (bfloat*)(ws + off); off += WBYTES;
  bfloat* wkt = (bfloat*)(ws + off); off += WBYTES;
  bfloat* wvt = (bfloat*)(ws + off); off += WBYTES;
  bfloat* wot = (bfloat*)(ws + off); off += WBYTES;
  bfloat* qmh = (bfloat*)(ws + off); off += XBYTES;
  bfloat* qml = (bfloat*)(ws + off); off += XBYTES;
  bfloat* kmh = (bfloat*)(ws + off); off += XBYTES;
  bfloat* kml = (bfloat*)(ws + off); off += XBYTES;
  bfloat* vtr = (bfloat*)(ws + off); off += XBYTES;  // V^T [B][D][S], key-permuted
  bfloat* attn = (bfloat*)(ws + off); off += XBYTES;

  hipMemsetAsync(sums, 0, 4 * sizeof(double), stream);
  prep_kernel<<<dim3(256, 4), 256, 0, stream>>>(wq, wk, wv, wo, sums);
  tern_kernel<<<dim3(128, 4), 256, 0, stream>>>(wq, wk, wv, wo, wqt, wkt, wvt, wot, sums);
  qkv_gemm<<<768, 256, 0, stream>>>(
      q_in, k_in, v_in, wqt, wkt, wvt, qmh, qml, kmh, kml, vtr);
  flash_kernel<<<512, 512, 0, stream>>>(qmh, qml, kmh, kml, vtr, attn);
  gemm_wo<<<512, 256, 0, stream>>>(attn, wot, outp);
}